// Round 2
// baseline (12909.312 us; speedup 1.0000x reference)
//
#include <hip/hip_runtime.h>

#define B_ 64
#define T_ 256
#define U_ 1024
#define G_ 4096   // 4*U
#define V_ 512
#define F_ 64
#define L_ 512

typedef __attribute__((ext_vector_type(4))) float f32x4;
typedef _Float16 f16;
typedef __attribute__((ext_vector_type(8))) f16 f16x8;

__device__ __forceinline__ f16x8 ld8(const f16* p) {
  return *reinterpret_cast<const f16x8*>(p);
}
__device__ __forceinline__ float sigm(float x) { return 1.f / (1.f + __expf(-x)); }
__device__ __forceinline__ float tanh_f(float x) {
  float xc = fminf(fmaxf(x, -15.f), 15.f);
  float e = __expf(2.f * xc);
  return (e - 1.f) / (e + 1.f);
}

// ---------------- prep kernels ----------------

// in [K][N] f32 row-major -> out [N][K] f16 row-major
__global__ __launch_bounds__(256) void transpose_f16(const float* in, f16* out, int K, int N) {
  __shared__ float tile[64][65];
  long n0 = (long)blockIdx.x * 64, k0 = (long)blockIdx.y * 64;
  int c = threadIdx.x & 63, r4 = threadIdx.x >> 6;
#pragma unroll
  for (int rr = 0; rr < 16; ++rr) {
    int row = rr * 4 + r4;
    tile[row][c] = in[(k0 + row) * N + n0 + c];
  }
  __syncthreads();
#pragma unroll
  for (int rr = 0; rr < 16; ++rr) {
    int nrow = rr * 4 + r4;
    out[(n0 + nrow) * K + k0 + c] = (f16)tile[c][nrow];
  }
}

__global__ void conv_f16(const float* in, f16* out, int n) {
  int i = blockIdx.x * 256 + threadIdx.x;
  if (i < n) out[i] = (f16)in[i];
}

// latA[b][j] = sum_k latent[b][k]*k1[k][j] + b1[j]   (fp32, time-invariant)
__global__ __launch_bounds__(256) void latA_kernel(const float* latent, const float* k1,
                                                   const float* b1, float* latA) {
  __shared__ float ls[8][512];
  int jc = blockIdx.x, bg = blockIdx.y;
  for (int i = threadIdx.x; i < 8 * 512; i += 256)
    ls[i >> 9][i & 511] = latent[(long)(bg * 8 + (i >> 9)) * L_ + (i & 511)];
  __syncthreads();
  int j = jc * 256 + threadIdx.x;
  float bv = b1[j];
  float acc[8];
#pragma unroll
  for (int i = 0; i < 8; ++i) acc[i] = bv;
  for (int k = 0; k < L_; ++k) {
    float w = k1[(long)k * G_ + j];
#pragma unroll
    for (int i = 0; i < 8; ++i) acc[i] += ls[i][k] * w;
  }
#pragma unroll
  for (int i = 0; i < 8; ++i) latA[(long)(bg * 8 + i) * G_ + j] = acc[i];
}

// ---------------- pipelined scan phase ----------------

struct PhaseP {
  const f16 *rk1T, *k2T, *rk2T, *k3T, *rk3T, *k1xT, *xf16;
  const float *latA, *b2, *b3;
  f16 *h1r, *h2r, *yall;
  float *c1, *c2, *c3;
};

// grid: 192 blocks x 64 threads. block = (layer = blk>>6, u-chunk = blk&63).
// Wave computes z[64 b][4 gates x 16 u] via MFMA 16x16x32 f16, then the LSTM
// cell update fully in-register (each lane's acc[mt][0..3][e] = i,f,g,o of one (b,u)).
__global__ __launch_bounds__(64) void phase_kernel(PhaseP P, int s) {
  int blk = blockIdx.x;
  int layer = blk >> 6;
  int uc = blk & 63;
  int t = s - layer;
  if (t < 0 || t >= T_) return;
  int lane = threadIdx.x;
  int lrow = lane & 15, lk = lane >> 4;
  int u0 = uc * 16;
  int rd = (s + 1) & 1, wr = s & 1;

  f32x4 acc[4][4];
  if (layer == 0) {
#pragma unroll
    for (int mt = 0; mt < 4; ++mt)
#pragma unroll
      for (int g = 0; g < 4; ++g) {
        const float* lp = P.latA + (long)(mt * 16 + lk * 4) * G_ + g * 1024 + u0 + lrow;
#pragma unroll
        for (int e = 0; e < 4; ++e) acc[mt][g][e] = lp[(long)e * G_];
      }
  } else {
    const float* bias = (layer == 1) ? P.b2 : P.b3;
#pragma unroll
    for (int g = 0; g < 4; ++g) {
      float bv = bias[g * 1024 + u0 + lrow];
#pragma unroll
      for (int mt = 0; mt < 4; ++mt)
#pragma unroll
        for (int e = 0; e < 4; ++e) acc[mt][g][e] = bv;
    }
  }

  auto mm1024 = [&](const f16* A, long astr, const f16* W) {
    for (int k0 = 0; k0 < 1024; k0 += 32) {
      f16x8 a[4], b[4];
#pragma unroll
      for (int mt = 0; mt < 4; ++mt)
        a[mt] = ld8(A + (long)(mt * 16 + lrow) * astr + k0 + lk * 8);
#pragma unroll
      for (int g = 0; g < 4; ++g)
        b[g] = ld8(W + (long)(g * 1024 + u0 + lrow) * 1024 + k0 + lk * 8);
#pragma unroll
      for (int mt = 0; mt < 4; ++mt)
#pragma unroll
        for (int g = 0; g < 4; ++g)
          acc[mt][g] = __builtin_amdgcn_mfma_f32_16x16x32_f16(a[mt], b[g], acc[mt][g], 0, 0, 0);
    }
  };

  if (layer == 0) {
    if (t > 0) mm1024(P.h1r + rd * (B_ * U_), U_, P.rk1T);
    // x-part: K=64 over k1 rows 512..575
    for (int k0 = 0; k0 < 64; k0 += 32) {
      f16x8 a[4], b[4];
#pragma unroll
      for (int mt = 0; mt < 4; ++mt)
        a[mt] = ld8(P.xf16 + (long)(mt * 16 + lrow) * (T_ * F_) + t * F_ + k0 + lk * 8);
#pragma unroll
      for (int g = 0; g < 4; ++g)
        b[g] = ld8(P.k1xT + (long)(g * 1024 + u0 + lrow) * F_ + k0 + lk * 8);
#pragma unroll
      for (int mt = 0; mt < 4; ++mt)
#pragma unroll
        for (int g = 0; g < 4; ++g)
          acc[mt][g] = __builtin_amdgcn_mfma_f32_16x16x32_f16(a[mt], b[g], acc[mt][g], 0, 0, 0);
    }
  } else if (layer == 1) {
    mm1024(P.h1r + rd * (B_ * U_), U_, P.k2T);              // input: h1(t)
    if (t > 0) mm1024(P.h2r + rd * (B_ * U_), U_, P.rk2T);  // recurrent: h2(t-1)
  } else {
    mm1024(P.h2r + rd * (B_ * U_), U_, P.k3T);              // input: h2(t)
    if (t > 0) mm1024(P.yall + (long)(t - 1) * U_, (long)T_ * U_, P.rk3T);  // h3(t-1)
  }

  float* cb = (layer == 0) ? P.c1 : (layer == 1) ? P.c2 : P.c3;
#pragma unroll
  for (int mt = 0; mt < 4; ++mt)
#pragma unroll
    for (int e = 0; e < 4; ++e) {
      int bb = mt * 16 + lk * 4 + e;   // batch row (C/D layout: row=(lane>>4)*4+e)
      int u = u0 + lrow;               // unit     (C/D layout: col=lane&15)
      float gi = sigm(acc[mt][0][e]);
      float gf = sigm(acc[mt][1][e]);
      float gg = tanh_f(acc[mt][2][e]);
      float go = sigm(acc[mt][3][e]);
      float cold = (t > 0) ? cb[(long)bb * U_ + u] : 0.f;
      float cn = gf * cold + gi * gg;
      cb[(long)bb * U_ + u] = cn;
      f16 hb = (f16)(go * tanh_f(cn));
      if (layer == 0)       P.h1r[wr * (B_ * U_) + (long)bb * U_ + u] = hb;
      else if (layer == 1)  P.h2r[wr * (B_ * U_) + (long)bb * U_ + u] = hb;
      else                  P.yall[(long)bb * (T_ * U_) + (long)t * U_ + u] = hb;
    }
}

// ---------------- projection + softmax ----------------

__global__ __launch_bounds__(256) void proj_kernel(const f16* yall, const f16* wT,
                                                   const float* bias, float* logits) {
  int wv = threadIdx.x >> 6, lane = threadIdx.x & 63;
  int lrow = lane & 15, lk = lane >> 4;
  long m0 = (long)blockIdx.y * 256 + wv * 64;
  int n0 = blockIdx.x * 64;
  f32x4 acc[4][4] = {};
  for (int k0 = 0; k0 < 1024; k0 += 32) {
    f16x8 a[4], b[4];
#pragma unroll
    for (int mt = 0; mt < 4; ++mt)
      a[mt] = ld8(yall + (m0 + mt * 16 + lrow) * U_ + k0 + lk * 8);
#pragma unroll
    for (int nt = 0; nt < 4; ++nt)
      b[nt] = ld8(wT + (long)(n0 + nt * 16 + lrow) * U_ + k0 + lk * 8);
#pragma unroll
    for (int mt = 0; mt < 4; ++mt)
#pragma unroll
      for (int nt = 0; nt < 4; ++nt)
        acc[mt][nt] = __builtin_amdgcn_mfma_f32_16x16x32_f16(a[mt], b[nt], acc[mt][nt], 0, 0, 0);
  }
#pragma unroll
  for (int mt = 0; mt < 4; ++mt)
#pragma unroll
    for (int nt = 0; nt < 4; ++nt)
#pragma unroll
      for (int e = 0; e < 4; ++e) {
        long row = m0 + mt * 16 + lk * 4 + e;
        int col = n0 + nt * 16 + lrow;
        logits[row * V_ + col] = acc[mt][nt][e] + bias[col];
      }
}

__global__ __launch_bounds__(256) void softmax_kernel(const float* logits, float* yout) {
  long row = (long)blockIdx.x * 4 + (threadIdx.x >> 6);
  int lane = threadIdx.x & 63;
  const float* lp = logits + row * V_;
  float vals[8];
#pragma unroll
  for (int j = 0; j < 8; ++j) vals[j] = lp[j * 64 + lane];
  float m = vals[0];
#pragma unroll
  for (int j = 1; j < 8; ++j) m = fmaxf(m, vals[j]);
  for (int off = 32; off > 0; off >>= 1) m = fmaxf(m, __shfl_xor(m, off));
  float sum = 0.f;
#pragma unroll
  for (int j = 0; j < 8; ++j) { vals[j] = __expf(vals[j] - m); sum += vals[j]; }
  for (int off = 32; off > 0; off >>= 1) sum += __shfl_xor(sum, off);
  float inv = 1.f / sum;
  float* yp = yout + row * V_;
#pragma unroll
  for (int j = 0; j < 8; ++j) yp[j * 64 + lane] = vals[j] * inv;
}

// ---------------- launch ----------------

extern "C" void kernel_launch(void* const* d_in, const int* in_sizes, int n_in,
                              void* d_out, int out_size, void* d_ws, size_t ws_size,
                              hipStream_t stream) {
  const float* latent = (const float*)d_in[0];
  const float* x      = (const float*)d_in[1];
  const float* k1     = (const float*)d_in[2];
  const float* rk1    = (const float*)d_in[3];
  const float* b1     = (const float*)d_in[4];
  const float* k2     = (const float*)d_in[5];
  const float* rk2    = (const float*)d_in[6];
  const float* b2     = (const float*)d_in[7];
  const float* k3     = (const float*)d_in[8];
  const float* rk3    = (const float*)d_in[9];
  const float* b3     = (const float*)d_in[10];
  const float* w      = (const float*)d_in[11];
  const float* bias   = (const float*)d_in[12];

  char* ws = (char*)d_ws;
  size_t o = 0;
  auto alloc = [&](size_t bytes) { size_t r = o; o += (bytes + 255) & ~(size_t)255; return r; };
  f16* rk1T = (f16*)(ws + alloc((size_t)G_ * U_ * 2));
  f16* k2T  = (f16*)(ws + alloc((size_t)G_ * U_ * 2));
  f16* rk2T = (f16*)(ws + alloc((size_t)G_ * U_ * 2));
  f16* k3T  = (f16*)(ws + alloc((size_t)G_ * U_ * 2));
  f16* rk3T = (f16*)(ws + alloc((size_t)G_ * U_ * 2));
  f16* k1xT = (f16*)(ws + alloc((size_t)G_ * F_ * 2));
  f16* wT   = (f16*)(ws + alloc((size_t)V_ * U_ * 2));
  f16* xf16 = (f16*)(ws + alloc((size_t)B_ * T_ * F_ * 2));
  float* latA = (float*)(ws + alloc((size_t)B_ * G_ * 4));
  f16* h1r  = (f16*)(ws + alloc((size_t)2 * B_ * U_ * 2));
  f16* h2r  = (f16*)(ws + alloc((size_t)2 * B_ * U_ * 2));
  float* c1 = (float*)(ws + alloc((size_t)B_ * U_ * 4));
  float* c2 = (float*)(ws + alloc((size_t)B_ * U_ * 4));
  float* c3 = (float*)(ws + alloc((size_t)B_ * U_ * 4));
  f16* yall = (f16*)(ws + alloc((size_t)B_ * T_ * U_ * 2));

  dim3 blk256(256);
  transpose_f16<<<dim3(G_ / 64, U_ / 64), blk256, 0, stream>>>(rk1, rk1T, U_, G_);
  transpose_f16<<<dim3(G_ / 64, U_ / 64), blk256, 0, stream>>>(k2, k2T, U_, G_);
  transpose_f16<<<dim3(G_ / 64, U_ / 64), blk256, 0, stream>>>(rk2, rk2T, U_, G_);
  transpose_f16<<<dim3(G_ / 64, U_ / 64), blk256, 0, stream>>>(k3, k3T, U_, G_);
  transpose_f16<<<dim3(G_ / 64, U_ / 64), blk256, 0, stream>>>(rk3, rk3T, U_, G_);
  transpose_f16<<<dim3(G_ / 64, 1), blk256, 0, stream>>>(k1 + (size_t)L_ * G_, k1xT, F_, G_);
  transpose_f16<<<dim3(V_ / 64, U_ / 64), blk256, 0, stream>>>(w, wT, U_, V_);
  conv_f16<<<dim3((B_ * T_ * F_ + 255) / 256), blk256, 0, stream>>>(x, xf16, B_ * T_ * F_);
  latA_kernel<<<dim3(16, 8), blk256, 0, stream>>>(latent, k1, b1, latA);

  PhaseP P{rk1T, k2T, rk2T, k3T, rk3T, k1xT, xf16, latA, b2, b3, h1r, h2r, yall, c1, c2, c3};
  for (int s = 0; s < T_ + 2; ++s)
    phase_kernel<<<dim3(192), dim3(64), 0, stream>>>(P, s);

  float* logits = (float*)d_out + (size_t)B_ * T_ * V_;
  proj_kernel<<<dim3(V_ / 64, (B_ * T_) / 256), blk256, 0, stream>>>(yall, wT, bias, logits);
  softmax_kernel<<<dim3(B_ * T_ / 4), blk256, 0, stream>>>(logits, (float*)d_out);
}

// Round 4
// 5585.776 us; speedup vs baseline: 2.3111x; 2.3111x over previous
//
#include <hip/hip_runtime.h>

#define B_ 64
#define T_ 256
#define U_ 1024
#define G_ 4096   // 4*U
#define V_ 512
#define F_ 64
#define L_ 512

typedef __attribute__((ext_vector_type(4))) float f32x4;
typedef _Float16 f16;
typedef __attribute__((ext_vector_type(8))) f16 f16x8;

__device__ __forceinline__ f16x8 ld8(const f16* p) {
  return *reinterpret_cast<const f16x8*>(p);
}
__device__ __forceinline__ float sigm(float x) { return 1.f / (1.f + __expf(-x)); }
__device__ __forceinline__ float tanh_f(float x) {
  float xc = fminf(fmaxf(x, -15.f), 15.f);
  float e = __expf(2.f * xc);
  return (e - 1.f) / (e + 1.f);
}

// ---------------- prep kernels ----------------

// in [K][N] f32 row-major -> out [N][K] f16 row-major
__global__ __launch_bounds__(256) void transpose_f16(const float* in, f16* out, int K, int N) {
  __shared__ float tile[64][65];
  long n0 = (long)blockIdx.x * 64, k0 = (long)blockIdx.y * 64;
  int c = threadIdx.x & 63, r4 = threadIdx.x >> 6;
#pragma unroll
  for (int rr = 0; rr < 16; ++rr) {
    int row = rr * 4 + r4;
    tile[row][c] = in[(k0 + row) * N + n0 + c];
  }
  __syncthreads();
#pragma unroll
  for (int rr = 0; rr < 16; ++rr) {
    int nrow = rr * 4 + r4;
    out[(n0 + nrow) * K + k0 + c] = (f16)tile[c][nrow];
  }
}

__global__ void conv_f16(const float* in, f16* out, int n) {
  int i = blockIdx.x * 256 + threadIdx.x;
  if (i < n) out[i] = (f16)in[i];
}

// latA[b][j] = sum_k latent[b][k]*k1[k][j] + b1[j]   (fp32, time-invariant)
__global__ __launch_bounds__(256) void latA_kernel(const float* latent, const float* k1,
                                                   const float* b1, float* latA) {
  __shared__ float ls[8][512];
  int jc = blockIdx.x, bg = blockIdx.y;
  for (int i = threadIdx.x; i < 8 * 512; i += 256)
    ls[i >> 9][i & 511] = latent[(long)(bg * 8 + (i >> 9)) * L_ + (i & 511)];
  __syncthreads();
  int j = jc * 256 + threadIdx.x;
  float bv = b1[j];
  float acc[8];
#pragma unroll
  for (int i = 0; i < 8; ++i) acc[i] = bv;
  for (int k = 0; k < L_; ++k) {
    float w = k1[(long)k * G_ + j];
#pragma unroll
    for (int i = 0; i < 8; ++i) acc[i] += ls[i][k] * w;
  }
#pragma unroll
  for (int i = 0; i < 8; ++i) latA[(long)(bg * 8 + i) * G_ + j] = acc[i];
}

// ---------------- pipelined scan phase ----------------

struct PhaseP {
  const f16 *rk1T, *k2T, *rk2T, *k3T, *rk3T, *k1xT, *xf16;
  const float *latA, *b2, *b3;
  f16 *h1r, *h2r, *yall;
  float *c1, *c2, *c3;
};

// grid: 192 blocks x 256 threads (4 waves). block = (layer = blk>>6, u-chunk = blk&63).
// The 4 waves split K (256 each); partial z reduced via LDS; 256 threads then do
// the LSTM cell update (4 (b,u) cells each).
__global__ __launch_bounds__(256, 1) void phase_kernel(PhaseP P, int s) {
  int blk = blockIdx.x;
  int layer = blk >> 6;
  int uc = blk & 63;
  int t = s - layer;
  if (t < 0 || t >= T_) return;
  int tid = threadIdx.x;
  int w = tid >> 6, lane = tid & 63;
  int lrow = lane & 15, lk = lane >> 4;
  int u0 = uc * 16;
  int rd = (s + 1) & 1, wr = s & 1;

  // zp[wave][gu][b(+pad)] : partial z, f32. pad 68 -> <=2-way bank conflicts.
  __shared__ float zp[4][64][68];

  f32x4 acc[4][4] = {};

  // one K-quarter (kbase..kbase+255) of A[64][astr] @ W^T slice
  auto mmq = [&](const f16* A, long astr, const f16* W) {
    int kbase = w * 256;
#pragma unroll
    for (int kk = 0; kk < 8; ++kk) {
      int k0 = kbase + kk * 32;
      f16x8 a[4], b[4];
#pragma unroll
      for (int mt = 0; mt < 4; ++mt)
        a[mt] = ld8(A + (long)(mt * 16 + lrow) * astr + k0 + lk * 8);
#pragma unroll
      for (int g = 0; g < 4; ++g)
        b[g] = ld8(W + (long)(g * 1024 + u0 + lrow) * 1024 + k0 + lk * 8);
#pragma unroll
      for (int mt = 0; mt < 4; ++mt)
#pragma unroll
        for (int g = 0; g < 4; ++g)
          acc[mt][g] = __builtin_amdgcn_mfma_f32_16x16x32_f16(a[mt], b[g], acc[mt][g], 0, 0, 0);
    }
  };

  if (layer == 0) {
    if (t > 0) mmq(P.h1r + rd * (B_ * U_), U_, P.rk1T);
    if (w == 0) {  // x-part: K=64, weight k1xT [G_][F_]
#pragma unroll
      for (int kk = 0; kk < 2; ++kk) {
        int k0 = kk * 32;
        f16x8 a[4], b[4];
#pragma unroll
        for (int mt = 0; mt < 4; ++mt)
          a[mt] = ld8(P.xf16 + (long)(mt * 16 + lrow) * (T_ * F_) + t * F_ + k0 + lk * 8);
#pragma unroll
        for (int g = 0; g < 4; ++g)
          b[g] = ld8(P.k1xT + (long)(g * 1024 + u0 + lrow) * F_ + k0 + lk * 8);
#pragma unroll
        for (int mt = 0; mt < 4; ++mt)
#pragma unroll
          for (int g = 0; g < 4; ++g)
            acc[mt][g] = __builtin_amdgcn_mfma_f32_16x16x32_f16(a[mt], b[g], acc[mt][g], 0, 0, 0);
      }
    }
  } else if (layer == 1) {
    mmq(P.h1r + rd * (B_ * U_), U_, P.k2T);              // input: h1(t)
    if (t > 0) mmq(P.h2r + rd * (B_ * U_), U_, P.rk2T);  // recurrent: h2(t-1)
  } else {
    mmq(P.h2r + rd * (B_ * U_), U_, P.k3T);              // input: h2(t)
    if (t > 0) mmq(P.yall + (long)(t - 1) * U_, (long)T_ * U_, P.rk3T);  // h3(t-1)
  }

  // write partials: acc[mt][g][e] -> b = mt*16+lk*4+e (contiguous in e), gu = g*16+lrow
#pragma unroll
  for (int mt = 0; mt < 4; ++mt)
#pragma unroll
    for (int g = 0; g < 4; ++g)
      *reinterpret_cast<f32x4*>(&zp[w][g * 16 + lrow][mt * 16 + lk * 4]) = acc[mt][g];
  __syncthreads();

  // cell update: thread -> b = tid>>2, u_local = 4*(tid&3) + i (i=0..3)
  {
    int b = tid >> 2;
    int j4 = (tid & 3) * 4;
    float zi[4], zf[4], zg[4], zo[4];
#pragma unroll
    for (int i = 0; i < 4; ++i) {
      int ul = j4 + i;
      zi[i] = zp[0][ul][b] + zp[1][ul][b] + zp[2][ul][b] + zp[3][ul][b];
      zf[i] = zp[0][16 + ul][b] + zp[1][16 + ul][b] + zp[2][16 + ul][b] + zp[3][16 + ul][b];
      zg[i] = zp[0][32 + ul][b] + zp[1][32 + ul][b] + zp[2][32 + ul][b] + zp[3][32 + ul][b];
      zo[i] = zp[0][48 + ul][b] + zp[1][48 + ul][b] + zp[2][48 + ul][b] + zp[3][48 + ul][b];
    }
    if (layer == 0) {
      const float* lp = P.latA + (long)b * G_ + u0 + j4;
#pragma unroll
      for (int i = 0; i < 4; ++i) {
        zi[i] += lp[i];
        zf[i] += lp[1024 + i];
        zg[i] += lp[2048 + i];
        zo[i] += lp[3072 + i];
      }
    } else {
      const float* bp = (layer == 1) ? P.b2 : P.b3;
#pragma unroll
      for (int i = 0; i < 4; ++i) {
        int u = u0 + j4 + i;
        zi[i] += bp[u];
        zf[i] += bp[1024 + u];
        zg[i] += bp[2048 + u];
        zo[i] += bp[3072 + u];
      }
    }

    float* cb = (layer == 0) ? P.c1 : (layer == 1) ? P.c2 : P.c3;
    float* cp = cb + (long)b * U_ + u0 + j4;
    f32x4 cold = {0.f, 0.f, 0.f, 0.f};
    if (t > 0) cold = *reinterpret_cast<const f32x4*>(cp);
    f32x4 cnew;
    unsigned short hpk[4];
#pragma unroll
    for (int i = 0; i < 4; ++i) {
      float gi = sigm(zi[i]);
      float gf = sigm(zf[i]);
      float gg = tanh_f(zg[i]);
      float go = sigm(zo[i]);
      float cn = gf * cold[i] + gi * gg;
      cnew[i] = cn;
      f16 hv = (f16)(go * tanh_f(cn));
      hpk[i] = *reinterpret_cast<unsigned short*>(&hv);
    }
    *reinterpret_cast<f32x4*>(cp) = cnew;
    unsigned long packed = (unsigned long)hpk[0] | ((unsigned long)hpk[1] << 16) |
                           ((unsigned long)hpk[2] << 32) | ((unsigned long)hpk[3] << 48);
    f16* hdst;
    if (layer == 0)       hdst = P.h1r + wr * (B_ * U_) + (long)b * U_ + u0 + j4;
    else if (layer == 1)  hdst = P.h2r + wr * (B_ * U_) + (long)b * U_ + u0 + j4;
    else                  hdst = P.yall + (long)b * (T_ * U_) + (long)t * U_ + u0 + j4;
    *reinterpret_cast<unsigned long*>(hdst) = packed;
  }
}

// ---------------- projection + softmax ----------------

__global__ __launch_bounds__(256) void proj_kernel(const f16* yall, const f16* wT,
                                                   const float* bias, float* logits) {
  int wv = threadIdx.x >> 6, lane = threadIdx.x & 63;
  int lrow = lane & 15, lk = lane >> 4;
  long m0 = (long)blockIdx.y * 256 + wv * 64;
  int n0 = blockIdx.x * 64;
  f32x4 acc[4][4] = {};
  for (int k0 = 0; k0 < 1024; k0 += 32) {
    f16x8 a[4], b[4];
#pragma unroll
    for (int mt = 0; mt < 4; ++mt)
      a[mt] = ld8(yall + (m0 + mt * 16 + lrow) * U_ + k0 + lk * 8);
#pragma unroll
    for (int nt = 0; nt < 4; ++nt)
      b[nt] = ld8(wT + (long)(n0 + nt * 16 + lrow) * U_ + k0 + lk * 8);
#pragma unroll
    for (int mt = 0; mt < 4; ++mt)
#pragma unroll
      for (int nt = 0; nt < 4; ++nt)
        acc[mt][nt] = __builtin_amdgcn_mfma_f32_16x16x32_f16(a[mt], b[nt], acc[mt][nt], 0, 0, 0);
  }
#pragma unroll
  for (int mt = 0; mt < 4; ++mt)
#pragma unroll
    for (int nt = 0; nt < 4; ++nt)
#pragma unroll
      for (int e = 0; e < 4; ++e) {
        long row = m0 + mt * 16 + lk * 4 + e;
        int col = n0 + nt * 16 + lrow;
        logits[row * V_ + col] = acc[mt][nt][e] + bias[col];
      }
}

__global__ __launch_bounds__(256) void softmax_kernel(const float* logits, float* yout) {
  long row = (long)blockIdx.x * 4 + (threadIdx.x >> 6);
  int lane = threadIdx.x & 63;
  const float* lp = logits + row * V_;
  float vals[8];
#pragma unroll
  for (int j = 0; j < 8; ++j) vals[j] = lp[j * 64 + lane];
  float m = vals[0];
#pragma unroll
  for (int j = 1; j < 8; ++j) m = fmaxf(m, vals[j]);
  for (int off = 32; off > 0; off >>= 1) m = fmaxf(m, __shfl_xor(m, off));
  float sum = 0.f;
#pragma unroll
  for (int j = 0; j < 8; ++j) { vals[j] = __expf(vals[j] - m); sum += vals[j]; }
  for (int off = 32; off > 0; off >>= 1) sum += __shfl_xor(sum, off);
  float inv = 1.f / sum;
  float* yp = yout + row * V_;
#pragma unroll
  for (int j = 0; j < 8; ++j) yp[j * 64 + lane] = vals[j] * inv;
}

// ---------------- launch ----------------

extern "C" void kernel_launch(void* const* d_in, const int* in_sizes, int n_in,
                              void* d_out, int out_size, void* d_ws, size_t ws_size,
                              hipStream_t stream) {
  const float* latent = (const float*)d_in[0];
  const float* x      = (const float*)d_in[1];
  const float* k1     = (const float*)d_in[2];
  const float* rk1    = (const float*)d_in[3];
  const float* b1     = (const float*)d_in[4];
  const float* k2     = (const float*)d_in[5];
  const float* rk2    = (const float*)d_in[6];
  const float* b2     = (const float*)d_in[7];
  const float* k3     = (const float*)d_in[8];
  const float* rk3    = (const float*)d_in[9];
  const float* b3     = (const float*)d_in[10];
  const float* w      = (const float*)d_in[11];
  const float* bias   = (const float*)d_in[12];

  char* ws = (char*)d_ws;
  size_t o = 0;
  auto alloc = [&](size_t bytes) { size_t r = o; o += (bytes + 255) & ~(size_t)255; return r; };
  f16* rk1T = (f16*)(ws + alloc((size_t)G_ * U_ * 2));
  f16* k2T  = (f16*)(ws + alloc((size_t)G_ * U_ * 2));
  f16* rk2T = (f16*)(ws + alloc((size_t)G_ * U_ * 2));
  f16* k3T  = (f16*)(ws + alloc((size_t)G_ * U_ * 2));
  f16* rk3T = (f16*)(ws + alloc((size_t)G_ * U_ * 2));
  f16* k1xT = (f16*)(ws + alloc((size_t)G_ * F_ * 2));
  f16* wT   = (f16*)(ws + alloc((size_t)V_ * U_ * 2));
  f16* xf16 = (f16*)(ws + alloc((size_t)B_ * T_ * F_ * 2));
  float* latA = (float*)(ws + alloc((size_t)B_ * G_ * 4));
  f16* h1r  = (f16*)(ws + alloc((size_t)2 * B_ * U_ * 2));
  f16* h2r  = (f16*)(ws + alloc((size_t)2 * B_ * U_ * 2));
  float* c1 = (float*)(ws + alloc((size_t)B_ * U_ * 4));
  float* c2 = (float*)(ws + alloc((size_t)B_ * U_ * 4));
  float* c3 = (float*)(ws + alloc((size_t)B_ * U_ * 4));
  f16* yall = (f16*)(ws + alloc((size_t)B_ * T_ * U_ * 2));

  dim3 blk256(256);
  transpose_f16<<<dim3(G_ / 64, U_ / 64), blk256, 0, stream>>>(rk1, rk1T, U_, G_);
  transpose_f16<<<dim3(G_ / 64, U_ / 64), blk256, 0, stream>>>(k2, k2T, U_, G_);
  transpose_f16<<<dim3(G_ / 64, U_ / 64), blk256, 0, stream>>>(rk2, rk2T, U_, G_);
  transpose_f16<<<dim3(G_ / 64, U_ / 64), blk256, 0, stream>>>(k3, k3T, U_, G_);
  transpose_f16<<<dim3(G_ / 64, U_ / 64), blk256, 0, stream>>>(rk3, rk3T, U_, G_);
  transpose_f16<<<dim3(G_ / 64, 1), blk256, 0, stream>>>(k1 + (size_t)L_ * G_, k1xT, F_, G_);
  transpose_f16<<<dim3(V_ / 64, U_ / 64), blk256, 0, stream>>>(w, wT, U_, V_);
  conv_f16<<<dim3((B_ * T_ * F_ + 255) / 256), blk256, 0, stream>>>(x, xf16, B_ * T_ * F_);
  latA_kernel<<<dim3(16, 8), blk256, 0, stream>>>(latent, k1, b1, latA);

  PhaseP P{rk1T, k2T, rk2T, k3T, rk3T, k1xT, xf16, latA, b2, b3, h1r, h2r, yall, c1, c2, c3};
  for (int s = 0; s < T_ + 2; ++s)
    phase_kernel<<<dim3(192), blk256, 0, stream>>>(P, s);

  float* logits = (float*)d_out + (size_t)B_ * T_ * V_;
  proj_kernel<<<dim3(V_ / 64, (B_ * T_) / 256), blk256, 0, stream>>>(yall, wT, bias, logits);
  softmax_kernel<<<dim3(B_ * T_ / 4), blk256, 0, stream>>>(logits, (float*)d_out);
}